// Round 18
// baseline (225.862 us; speedup 1.0000x reference)
//
#include <hip/hip_runtime.h>
#include <hip/hip_bf16.h>

#define H 500
#define D_IN 512
#define D_OUT 100
#define STEPS 49
#define NWG 8
#define SENT 0xFFFFFFFFu

typedef _Float16 h2_t __attribute__((ext_vector_type(2)));

#if defined(__has_builtin)
#if __has_builtin(__builtin_amdgcn_fdot2)
#define HAVE_FDOT2 1
#endif
#endif

__device__ __forceinline__ float fdot2f(h2_t a, h2_t b, float c) {
#ifdef HAVE_FDOT2
    return __builtin_amdgcn_fdot2(a, b, c, false);
#else
    return c + (float)a[0] * (float)b[0] + (float)a[1] * (float)b[1];
#endif
}
__device__ __forceinline__ h2_t bch2(unsigned u) { return __builtin_bit_cast(h2_t, u); }
__device__ __forceinline__ unsigned pk(float a, float b) {
    return __builtin_bit_cast(unsigned, h2_t{(_Float16)a, (_Float16)b});
}
__device__ __forceinline__ float tanh_fast(float x) {
    const float e = __expf(2.f * x);
    return 1.f - 2.f / (e + 1.f);
}
__device__ __forceinline__ int clen(int g) { return (g < 7) ? 64 : (H - 448); }  // 52
__device__ __forceinline__ unsigned aload(const float* p) {
    return __builtin_bit_cast(unsigned,
        __hip_atomic_load(p, __ATOMIC_RELAXED, __HIP_MEMORY_SCOPE_AGENT));
}
__device__ __forceinline__ void astore(float* p, float v) {
    __hip_atomic_store(p, v, __ATOMIC_RELAXED, __HIP_MEMORY_SCOPE_AGENT);
}

// ---------------- K1: xproj (blocks 0..62, x staged in LDS) + sentinel-fill of
// part+Hs (blocks 63..87; 50176 float4, 4 per thread).
__global__ void __launch_bounds__(512, 1)
k1_xproj(const float* __restrict__ x, const float* __restrict__ W_ih,
         const float* __restrict__ b_ih, const float* __restrict__ b_hh,
         float* __restrict__ xproj, float* __restrict__ sentreg) {
    if (blockIdx.x >= 63) {
        const int b = blockIdx.x - 63;                 // 0..24
        float4* p4 = (float4*)sentreg;                 // part+Hs contiguous
        const float4 s4 = {__builtin_bit_cast(float, SENT), __builtin_bit_cast(float, SENT),
                           __builtin_bit_cast(float, SENT), __builtin_bit_cast(float, SENT)};
        const int base = b * 512 + (int)threadIdx.x;   // 0..12799
#pragma unroll
        for (int j = 0; j < 4; j++) {
            const int idx = j * 12800 + base;
            if (idx < 50176) p4[idx] = s4;             // (702464+100352)/16
        }
        return;
    }
    __shared__ float xl[D_IN * STEPS];                 // 100352 B
    const int tid = threadIdx.x;
    for (int i = tid; i < D_IN * STEPS; i += 512) xl[i] = x[i];
    __syncthreads();

    const int wv = tid >> 6, lane = tid & 63;
    const int r = blockIdx.x * 8 + wv;                 // 0..503
    if (r >= H) return;
    float wr8[8];
#pragma unroll
    for (int k = 0; k < 8; k++) wr8[k] = W_ih[r * D_IN + k * 64 + lane];
    float p[STEPS];
#pragma unroll
    for (int t = 0; t < STEPS; t++) p[t] = 0.f;
#pragma unroll
    for (int k = 0; k < 8; k++) {
        const float* xr = xl + (k * 64 + lane) * STEPS;
#pragma unroll
        for (int t = 0; t < STEPS; t++) p[t] = fmaf(wr8[k], xr[t], p[t]);
    }
#pragma unroll
    for (int t = 0; t < STEPS; t++) {
        float v = p[t];
        v += __shfl_xor(v, 32); v += __shfl_xor(v, 16); v += __shfl_xor(v, 8);
        v += __shfl_xor(v, 4);  v += __shfl_xor(v, 2);  v += __shfl_xor(v, 1);
        p[t] = v;
    }
    if (lane == 0) {
        const float b = b_ih[r] + b_hh[r];
        for (int t = 0; t < STEPS; t++) xproj[t * 512 + r] = p[t] + b;
    }
}

// ---------------- K2: 8-WG column-split scan + fused output head.
// WG g owns h-chunk g (rows [64g, 64g+clen(g))) and W_hh[:, 64g..64g+64) in LDS
// (64 KB f16). Thread (rr = tid>>3, sub = tid&7): row-in-chunk rr, 8-col slice.
// Per step: 8 dests x {1 uint4 LDS read, 4 fdot2, 3 shfl reduce}; 7 remote sends
// (agent store, slot j = 6-k); poll 7 slots (pipelined agent loads, sentinel).
// Hs written via one-step-DELAYED agent stores (flight hidden under next step).
// Post-scan: WG g computes out[t] for t = g, g+8, ... by polling sentinel Hs.
__global__ void __launch_bounds__(512, 1)
k2_scan(const float* __restrict__ hidden0, const float* __restrict__ W_hh,
        const float* __restrict__ xproj, float* part, float* Hs,
        const float* __restrict__ W_out, const float* __restrict__ b_out,
        float* __restrict__ out) {
    __shared__ uint4 wl[NWG * 512];                 // 65536 B
    __shared__ __align__(16) _Float16 hch[2][64];   // 256 B

    const int g = blockIdx.x, tid = threadIdx.x;
    const int rr = tid >> 3, sub = tid & 7;
    const int myLen = clen(g);
    const bool epi = (sub == 0) && (rr < myLen);

    // ---- preamble: W_hh[64d+rr][64g+8sub .. +8] -> wl[d*512+tid] (f16 pairs) ----
#pragma unroll
    for (int d = 0; d < NWG; d++) {
        uint4 u = {0u, 0u, 0u, 0u};
        const int row = 64 * d + rr;
        if (row < H) {
            const float* rowp = W_hh + (size_t)row * H + 64 * g + 8 * sub;
            const int cmax = (H - 64 * g) - 8 * sub;   // valid cols: cc < cmax
            if (cmax >= 8) {
                const float4 f0 = *(const float4*)(rowp);
                const float4 f1 = *(const float4*)(rowp + 4);
                u.x = pk(f0.x, f0.y); u.y = pk(f0.z, f0.w);
                u.z = pk(f1.x, f1.y); u.w = pk(f1.z, f1.w);
            } else if (cmax > 0) {
                float f[8];
#pragma unroll
                for (int cc = 0; cc < 8; cc++) f[cc] = (cc < cmax) ? rowp[cc] : 0.f;
                u.x = pk(f[0], f[1]); u.y = pk(f[2], f[3]);
                u.z = pk(f[4], f[5]); u.w = pk(f[6], f[7]);
            }
        }
        wl[d * 512 + tid] = u;
    }
    if (tid < 64) hch[0][tid] = (tid < myLen) ? (_Float16)hidden0[64 * g + tid]
                                              : (_Float16)0.f;
    else if (tid < 128) hch[1][tid - 64] = (_Float16)0.f;
    __syncthreads();

    float prevHv = 0.f;
#pragma unroll 1
    for (int t = 0; t < STEPS; ++t) {
        const int cur = t & 1;
        if (t > 0 && epi) astore(&Hs[(t - 1) * 512 + 64 * g + rr], prevHv);  // delayed
        float xp = 0.f;
        if (epi) xp = xproj[t * 512 + 64 * g + rr];    // plain (k1 complete)

        const uint4 hb = ((const uint4*)&hch[cur][0])[sub];   // 8 cols = 4 pairs
        float own = 0.f;
#pragma unroll
        for (int k = 0; k < 8; k++) {
            const int d = (g + 1 + k) & 7;             // k=0..6 remote, k=7 own
            const uint4 w = wl[d * 512 + tid];
            float s = fdot2f(bch2(w.x), bch2(hb.x), 0.f);
            s = fdot2f(bch2(w.y), bch2(hb.y), s);
            s = fdot2f(bch2(w.z), bch2(hb.z), s);
            s = fdot2f(bch2(w.w), bch2(hb.w), s);
            s += __shfl_xor(s, 1);                     // reduce 8 col-subs
            s += __shfl_xor(s, 2);
            s += __shfl_xor(s, 4);
            if (k < 7) {
                if (sub == 0)                          // slot j = 6-k (src-distinct)
                    astore(&part[((t * 8 + d) * 7 + (6 - k)) * 64 + rr], s);
            } else own = s;
        }

        if (epi) {
            const float* pb = &part[(t * 8 + g) * 7 * 64];
            unsigned bb[7];
#pragma unroll
            for (int j = 0; j < 7; j++) bb[j] = SENT;
            bool all;
            do {                                       // 7 pipelined MALL loads/iter
                all = true;
#pragma unroll
                for (int j = 0; j < 7; j++)
                    if (bb[j] == SENT) {
                        bb[j] = aload(&pb[j * 64 + rr]);
                        if (bb[j] == SENT) all = false;
                    }
            } while (!all);
            float tot = own + xp;
#pragma unroll
            for (int j = 0; j < 7; j++) tot += __builtin_bit_cast(float, bb[j]);
            const float hv = tanh_fast(tot);
            prevHv = hv;
            hch[cur ^ 1][rr] = (_Float16)hv;           // pads (rr>=myLen) stay 0
        }
        __syncthreads();
    }
    if (epi) astore(&Hs[(STEPS - 1) * 512 + 64 * g + rr], prevHv);

    // ---- fused output head: t = g, g+8, ... (polls sentinel Hs; all near-landed) ----
    float* hsm = (float*)wl;                           // weights dead, reuse LDS
    for (int tt = g; tt < STEPS; tt += NWG) {
        if (tid < H) {
            unsigned hb2 = aload(&Hs[tt * 512 + tid]);
            while (hb2 == SENT) hb2 = aload(&Hs[tt * 512 + tid]);
            hsm[tid] = __builtin_bit_cast(float, hb2);
        }
        __syncthreads();
        const int o = tid >> 2, q4 = tid & 3;
        if (o < D_OUT) {
            float s = 0.f;
            const float* wr_ = W_out + o * H + q4;
            const float* hr_ = hsm + q4;
#pragma unroll 5
            for (int j = 0; j < 125; j++) s = fmaf(wr_[4 * j], hr_[4 * j], s);
            s += __shfl_xor(s, 1);
            s += __shfl_xor(s, 2);
            if (q4 == 0) out[tt * D_OUT + o] = tanh_fast(s + b_out[o]);
        }
        __syncthreads();
    }
}

extern "C" void kernel_launch(void* const* d_in, const int* in_sizes, int n_in,
                              void* d_out, int out_size, void* d_ws, size_t ws_size,
                              hipStream_t stream) {
    const float* x       = (const float*)d_in[0];
    const float* hidden0 = (const float*)d_in[1];
    const float* W_ih    = (const float*)d_in[2];
    const float* W_hh    = (const float*)d_in[3];
    const float* b_ih    = (const float*)d_in[4];
    const float* b_hh    = (const float*)d_in[5];
    const float* W_out   = (const float*)d_in[6];
    const float* b_out   = (const float*)d_in[7];
    float* out = (float*)d_out;

    char* ws = (char*)d_ws;
    float* part  = (float*)ws;                     // 49*8*7*64*4 = 702464 (sentinel)
    float* Hs    = (float*)(ws + 702464);          // 100352          (sentinel)
    float* xproj = (float*)(ws + 802816);          // 100352  (total 903168)

    k1_xproj<<<88, 512, 0, stream>>>(x, W_ih, b_ih, b_hh, xproj, part /*sentreg*/);
    k2_scan<<<NWG, 512, 0, stream>>>(hidden0, W_hh, xproj, part, Hs, W_out, b_out, out);
}

// Round 19
// 100.105 us; speedup vs baseline: 2.2562x; 2.2562x over previous
//
#include <hip/hip_runtime.h>
#include <hip/hip_bf16.h>

#define H 500
#define D_IN 512
#define D_OUT 100
#define STEPS 49
#define NWG 4
#define SENT 0xFFFFFFFFu

typedef _Float16 h2_t __attribute__((ext_vector_type(2)));

#if defined(__has_builtin)
#if __has_builtin(__builtin_amdgcn_fdot2)
#define HAVE_FDOT2 1
#endif
#endif

__device__ __forceinline__ float fdot2f(h2_t a, h2_t b, float c) {
#ifdef HAVE_FDOT2
    return __builtin_amdgcn_fdot2(a, b, c, false);
#else
    return c + (float)a[0] * (float)b[0] + (float)a[1] * (float)b[1];
#endif
}
__device__ __forceinline__ h2_t bch2(unsigned u) { return __builtin_bit_cast(h2_t, u); }
__device__ __forceinline__ unsigned pk(float a, float b) {
    return __builtin_bit_cast(unsigned, h2_t{(_Float16)a, (_Float16)b});
}
__device__ __forceinline__ float tanh_fast(float x) {
    const float e = __expf(2.f * x);
    return 1.f - 2.f / (e + 1.f);
}
__device__ __forceinline__ int clen(int g) { return (g < 3) ? 128 : (H - 384); }  // 116

// ---------------- K1: xproj + sentinel-init of part.
// Blocks 0..62: stage x (100 KB) in LDS once; 8 waves x 1 row each:
//   xproj[t*512+r] = b_ih[r]+b_hh[r]+sum_d x_lds[d][t]*W_ih[r][d], r = 8*blk+wave.
// Blocks 63..87: sentinel-fill part (25088 float4; 2 float4 per thread).
__global__ void __launch_bounds__(512, 1)
k1_xproj(const float* __restrict__ x, const float* __restrict__ W_ih,
         const float* __restrict__ b_ih, const float* __restrict__ b_hh,
         float* __restrict__ xproj, float* __restrict__ part) {
    if (blockIdx.x >= 63) {
        // sentinel helper: part is 49*4*4*128 floats = 25088 float4
        const int b = blockIdx.x - 63;                 // 0..24
        float4* p4 = (float4*)part;
        const float4 s4 = {__builtin_bit_cast(float, SENT), __builtin_bit_cast(float, SENT),
                           __builtin_bit_cast(float, SENT), __builtin_bit_cast(float, SENT)};
        const int i0 = b * 1024 + threadIdx.x;         // two halves: full 1024 coverage
        const int i1 = i0 + 512;
        if (i0 < 25088) p4[i0] = s4;
        if (i1 < 25088) p4[i1] = s4;
        return;
    }
    __shared__ float xl[D_IN * STEPS];                 // 100352 B
    const int tid = threadIdx.x;
    // stage x: coalesced (x is [512][49] contiguous = 25088 floats)
    for (int i = tid; i < D_IN * STEPS; i += 512) xl[i] = x[i];
    __syncthreads();

    const int wv = tid >> 6, lane = tid & 63;
    const int r = blockIdx.x * 8 + wv;                 // 0..503
    if (r >= H) return;
    float wr8[8];
#pragma unroll
    for (int k = 0; k < 8; k++) wr8[k] = W_ih[r * D_IN + k * 64 + lane];
    float p[STEPS];
#pragma unroll
    for (int t = 0; t < STEPS; t++) p[t] = 0.f;
#pragma unroll
    for (int k = 0; k < 8; k++) {
        const float* xr = xl + (k * 64 + lane) * STEPS;
#pragma unroll
        for (int t = 0; t < STEPS; t++) p[t] = fmaf(wr8[k], xr[t], p[t]);
    }
#pragma unroll
    for (int t = 0; t < STEPS; t++) {
        float v = p[t];
        v += __shfl_xor(v, 32); v += __shfl_xor(v, 16); v += __shfl_xor(v, 8);
        v += __shfl_xor(v, 4);  v += __shfl_xor(v, 2);  v += __shfl_xor(v, 1);
        p[t] = v;
    }
    if (lane == 0) {
        const float b = b_ih[r] + b_hh[r];
        for (int t = 0; t < STEPS; t++) xproj[t * 512 + r] = p[t] + b;
    }
}

// ---------------- K2: column-split dataflow scan (r11 structure; proven floor).
__global__ void __launch_bounds__(512, 1)
k2_scan(const float* __restrict__ hidden0, const float* __restrict__ W_hh,
        const float* __restrict__ xproj, float* part, float* __restrict__ Hs) {
    __shared__ uint4 wl[16 * 512];                  // 131072 B
    __shared__ __align__(16) _Float16 hch[2][128];  // 512 B

    const int g = blockIdx.x, tid = threadIdx.x;
    const int rr = tid >> 2, sub = tid & 3;
    const int myLen = clen(g);

    // preamble: W_hh[:, 128g + 32sub .. +32), rows 128d+rr -> LDS f16
#pragma unroll
    for (int d = 0; d < 4; d++) {
        uint4 u[4] = {{0,0,0,0},{0,0,0,0},{0,0,0,0},{0,0,0,0}};
        if (rr < clen(d)) {
            const int row = 128 * d + rr;
            const float* rowp = W_hh + (size_t)row * H + 128 * g + 32 * sub;
            const int cmax = myLen - 32 * sub;      // valid cols: cc < cmax
            if (cmax >= 32) {                       // aligned fast path (16B)
#pragma unroll
                for (int q8 = 0; q8 < 4; q8++) {
                    const float4 f0 = *(const float4*)(rowp + 8 * q8);
                    const float4 f1 = *(const float4*)(rowp + 8 * q8 + 4);
                    u[q8].x = pk(f0.x, f0.y); u[q8].y = pk(f0.z, f0.w);
                    u[q8].z = pk(f1.x, f1.y); u[q8].w = pk(f1.z, f1.w);
                }
            } else {                                // boundary (g==3, sub==3)
                float f[32];
#pragma unroll
                for (int cc = 0; cc < 32; cc++) f[cc] = (cc < cmax) ? rowp[cc] : 0.f;
#pragma unroll
                for (int q8 = 0; q8 < 4; q8++) {
                    u[q8].x = pk(f[8*q8+0], f[8*q8+1]);
                    u[q8].y = pk(f[8*q8+2], f[8*q8+3]);
                    u[q8].z = pk(f[8*q8+4], f[8*q8+5]);
                    u[q8].w = pk(f[8*q8+6], f[8*q8+7]);
                }
            }
        }
#pragma unroll
        for (int c = 0; c < 4; c++) wl[(d * 4 + c) * 512 + tid] = u[c];
    }
    if (tid < 128) hch[0][tid] = (tid < myLen) ? (_Float16)hidden0[128 * g + tid]
                                               : (_Float16)0.f;
    else if (tid < 256) hch[1][tid - 128] = (_Float16)0.f;
    __syncthreads();

#pragma unroll 1
    for (int t = 0; t < STEPS; ++t) {
        const int cur = t & 1;
        float xp = 0.f;
        if (sub == 0 && rr < myLen) xp = xproj[t * 512 + 128 * g + rr];  // early

        const uint4* hc = (const uint4*)&hch[cur][0];
        uint4 hv4[4];
#pragma unroll
        for (int c = 0; c < 4; c++) hv4[c] = hc[sub * 4 + c];   // broadcast reads

        float own = 0.f;
#pragma unroll
        for (int k = 0; k < 4; k++) {
            const int d = (g + 1 + k) & 3;          // k=0..2 remote, k=3 own
            float s = 0.f;
#pragma unroll
            for (int c = 0; c < 4; c++) {
                const uint4 w = wl[(d * 4 + c) * 512 + tid];
                const uint4 hb = hv4[c];
                s = fdot2f(bch2(w.x), bch2(hb.x), s);
                s = fdot2f(bch2(w.y), bch2(hb.y), s);
                s = fdot2f(bch2(w.z), bch2(hb.z), s);
                s = fdot2f(bch2(w.w), bch2(hb.w), s);
            }
            s += __shfl_xor(s, 1);                  // reduce 4 col-quarters
            s += __shfl_xor(s, 2);
            if (k < 3) {
                if (sub == 0)
                    __hip_atomic_store(&part[((t * 4 + d) * 4 + g) * 128 + rr], s,
                                       __ATOMIC_RELAXED, __HIP_MEMORY_SCOPE_AGENT);
            } else own = s;
        }

        if (sub == 0 && rr < myLen) {
            const int g1 = (g + 1) & 3, g2 = (g + 2) & 3, g3 = (g + 3) & 3;
            const float* pb = &part[(t * 4 + g) * 4 * 128];
            unsigned b1 = SENT, b2 = SENT, b3 = SENT;
            do {                                    // 3 pipelined MALL loads/iter
                if (b1 == SENT) b1 = __builtin_bit_cast(unsigned,
                    __hip_atomic_load(&pb[g1 * 128 + rr], __ATOMIC_RELAXED,
                                      __HIP_MEMORY_SCOPE_AGENT));
                if (b2 == SENT) b2 = __builtin_bit_cast(unsigned,
                    __hip_atomic_load(&pb[g2 * 128 + rr], __ATOMIC_RELAXED,
                                      __HIP_MEMORY_SCOPE_AGENT));
                if (b3 == SENT) b3 = __builtin_bit_cast(unsigned,
                    __hip_atomic_load(&pb[g3 * 128 + rr], __ATOMIC_RELAXED,
                                      __HIP_MEMORY_SCOPE_AGENT));
            } while (b1 == SENT || b2 == SENT || b3 == SENT);
            const float tot = own + __builtin_bit_cast(float, b1)
                                  + __builtin_bit_cast(float, b2)
                                  + __builtin_bit_cast(float, b3) + xp;
            const float hv = tanh_fast(tot);
            Hs[t * 512 + 128 * g + rr] = hv;
            hch[cur ^ 1][rr] = (_Float16)hv;        // pads (rr>=myLen) stay 0
        }
        __syncthreads();
    }
}

// ---------------- K3: out[t][o] = tanh(b_out[o] + sum_c Hs[t][c]*W_out[o][c])
__global__ void k3_out(const float* __restrict__ Hs, const float* __restrict__ W_out,
                       const float* __restrict__ b_out, float* __restrict__ out) {
    const int t = blockIdx.x, o = threadIdx.x;
    if (o < D_OUT) {
        const float4* wr = (const float4*)(W_out + o * H);
        const float4* hr = (const float4*)(Hs + t * 512);
        float acc = b_out[o];
#pragma unroll 5
        for (int i = 0; i < 125; i++) {
            const float4 wv = wr[i];
            const float4 hv = hr[i];
            acc = fmaf(wv.x, hv.x, acc);
            acc = fmaf(wv.y, hv.y, acc);
            acc = fmaf(wv.z, hv.z, acc);
            acc = fmaf(wv.w, hv.w, acc);
        }
        out[t * D_OUT + o] = tanh_fast(acc);
    }
}

extern "C" void kernel_launch(void* const* d_in, const int* in_sizes, int n_in,
                              void* d_out, int out_size, void* d_ws, size_t ws_size,
                              hipStream_t stream) {
    const float* x       = (const float*)d_in[0];
    const float* hidden0 = (const float*)d_in[1];
    const float* W_ih    = (const float*)d_in[2];
    const float* W_hh    = (const float*)d_in[3];
    const float* b_ih    = (const float*)d_in[4];
    const float* b_hh    = (const float*)d_in[5];
    const float* W_out   = (const float*)d_in[6];
    const float* b_out   = (const float*)d_in[7];
    float* out = (float*)d_out;

    char* ws = (char*)d_ws;
    float* part  = (float*)ws;                     // 49*4*4*128*4 = 401408 (sentinel)
    float* xproj = (float*)(ws + 401408);          // 49*512*4 = 100352
    float* Hs    = (float*)(ws + 501760);          // 100352   (total 602112)

    k1_xproj<<<88, 512, 0, stream>>>(x, W_ih, b_ih, b_hh, xproj, part);
    k2_scan<<<NWG, 512, 0, stream>>>(hidden0, W_hh, xproj, part, Hs);
    k3_out<<<STEPS, 128, 0, stream>>>(Hs, W_out, b_out, out);
}